// Round 10
// baseline (180.748 us; speedup 1.0000x reference)
//
#include <hip/hip_runtime.h>

// ---------------------------------------------------------------------------
// KernelClassifier: px = x@Wp+bp; pX = X@Wp+bp; Kis = exp(-||px-pX||^2/256)
// (drop self: Kis<1.0f), pred[b,lab[i]] += Kis[b,i], normalize, rank-gather.
// R4: fp32 LDS atomicAdd was a CAS loop -> fixed-point ds_add_u32 (451->216us).
// R5-R7: direct per-lane A-loads uncoalesced (64 lines/wave-instr) ~93us.
// R8/R9: global_load_lds staging, 2-phase + __syncthreads: barrier forces
//     vmcnt(0) drain of a stage issued only ~200cyc earlier; 4 waves parked
//     together, ~3 barrier-groups/CU -> latency exposed. Total regressed.
// R10: BARRIER-FREE staging. Each wave stages/reads only its own 16-row LDS
//     quarter (producer==consumer) -> no __syncthreads. Per-wave discipline:
//     vmcnt(0) before consume, lgkmcnt(0)+sched_barrier before overwrite.
//     16-20 independent wave-pipelines/CU; BW via TLP.
// ---------------------------------------------------------------------------

typedef short  bf8v  __attribute__((ext_vector_type(8)));   // 8 x bf16 (4 VGPR)
typedef float  f32x4 __attribute__((ext_vector_type(4)));   // MFMA C/D

#define NTRAIN 50000
#define NPAD   50048          // 391 * 128
#define NTILES 391
#define BQ     1024
#define DIN    768
#define DP     128
#define NCLS   100
#define PSTRIDE 104           // LDS pred row stride (u32); 128*104*4=53248B
#define PCOLS  104            // partial row width (>=100, float2-aligned)
#define FIXS   2097152.0f     // 2^21 fixed-point scale
#define FIXI   (1.0f / 2097152.0f)

__device__ __forceinline__ short f2bf(float x) {   // fp32 -> bf16 RNE
    unsigned u = __float_as_uint(x);
    u += 0x7FFFu + ((u >> 16) & 1u);
    return (short)(u >> 16);
}

// global_load_lds pointer casts (CK-style integer detour: LDS flat addresses
// carry the aperture in the high 32 bits, byte offset in the low 32).
#define AS1U(p) ((const __attribute__((address_space(1))) unsigned int*)(unsigned long long)(p))
#define AS3U(p) ((__attribute__((address_space(3))) unsigned int*)(unsigned int)(unsigned long long)(p))

// ---------------------------------------------------------------------------
// Kernel 0: pack Wp into B-fragment order: WpP[q][cb][lane][j] =
//   bf16(Wp[32q + 8*(lane>>4) + j][16cb + (lane&15)])
// ---------------------------------------------------------------------------
__global__ __launch_bounds__(256) void k_pack_wp(const float* __restrict__ Wp,
                                                 short* __restrict__ WpP) {
    int tid = blockIdx.x * 256 + threadIdx.x;
    if (tid >= 24 * 8 * 64) return;
    int l = tid & 63, cb = (tid >> 6) & 7, q = tid >> 9;
    int c = cb * 16 + (l & 15);
    int g = l >> 4;
    bf8v o;
#pragma unroll
    for (int j = 0; j < 8; ++j) {
        int k = q * 32 + g * 8 + j;
        o[j] = f2bf(Wp[k * DP + c]);
    }
    *reinterpret_cast<bf8v*>(WpP + (size_t)tid * 8) = o;
}

// ---------------------------------------------------------------------------
// Kernel 1: projection GEMM  out = rows @ Wp + bp   (K=768, Ncols=128)
// BM=64, 4 waves, wave = 16 rows x 128 cols, BARRIER-FREE.
// Per K-tile (64 cols): each wave async-stages its own 16x64 fp32 quarter
// (4 x global_load_lds width16, coalesced; granule c4 stored at c4^(r&7)),
// double-buffered. Consume: vmcnt(0) -> 4x ds_read_b128 (swizzled slots,
// 2-way bank floor) -> lgkmcnt(0)+sched_barrier -> stage next -> f2bf+MFMA.
// ---------------------------------------------------------------------------
__global__ __launch_bounds__(256) void k_proj(const float* __restrict__ Xin,
                                              const short* __restrict__ WpP,
                                              const float* __restrict__ bp,
                                              short* __restrict__ outP,
                                              float* __restrict__ normv,
                                              int Mreal) {
    __shared__ __align__(16) float Xlds[2][64 * 64];   // 2 x 16 KB fp32 tiles
    const int tid = threadIdx.x;
    const int w = tid >> 6, l = tid & 63, g = l >> 4, li = l & 15;
    const int rowblk = blockIdx.x * 64;

    f32x4 acc[8];
#pragma unroll
    for (int cb = 0; cb < 8; ++cb) acc[cb] = (f32x4){0.f, 0.f, 0.f, 0.f};

    // stage: wave w's 16x64 fp32 quarter of K-tile kb into lbuf (linear dest,
    // inverse-swizzled global source; rule #21 pair with swizzled read)
#define STAGE64(lbuf, kb)                                                     \
    {                                                                         \
        _Pragma("unroll")                                                     \
        for (int it = 0; it < 4; ++it) {                                      \
            int s  = w * 256 + it * 64 + l;      /* dest granule slot */      \
            int r  = s >> 4;                                                  \
            int c4 = (s & 15) ^ (r & 7);         /* logical granule */        \
            int rg = rowblk + r;                                              \
            rg = (rg < Mreal) ? rg : (Mreal - 1);                             \
            const float* gp = Xin + (size_t)rg * DIN + (kb) * 64 + c4 * 4;    \
            const float* lp = (lbuf) + (w * 256 + it * 64) * 4;               \
            __builtin_amdgcn_global_load_lds(AS1U(gp), AS3U(lp), 16, 0, 0);   \
        }                                                                     \
    }

    STAGE64(&Xlds[0][0], 0);

#pragma unroll
    for (int kb = 0; kb < 12; ++kb) {
        // wait: stage(kb) retired (it is the oldest outstanding VMEM group;
        // full drain is TLP-safe: 16-20 independent waves/CU cover latency)
        asm volatile("s_waitcnt vmcnt(0)" ::: "memory");
        const float* rbase = &Xlds[kb & 1][0] + (w * 16 + li) * 64;
        float4 a[4];
#pragma unroll
        for (int kc = 0; kc < 2; ++kc) {
            int s0 = (kc * 8 + g * 2)     ^ (li & 7);
            int s1 = (kc * 8 + g * 2 + 1) ^ (li & 7);
            a[kc * 2]     = *reinterpret_cast<const float4*>(rbase + s0 * 4);
            a[kc * 2 + 1] = *reinterpret_cast<const float4*>(rbase + s1 * 4);
        }
        // reads retired before the overwriting stage can be issued
        asm volatile("s_waitcnt lgkmcnt(0)" ::: "memory");
        __builtin_amdgcn_sched_barrier(0);
        if (kb + 1 < 12) STAGE64(&Xlds[(kb + 1) & 1][0], kb + 1);

#pragma unroll
        for (int kc = 0; kc < 2; ++kc) {
            const int q = kb * 2 + kc;
            float4 a0 = a[kc * 2], a1 = a[kc * 2 + 1];
            bf8v af;
            af[0] = f2bf(a0.x); af[1] = f2bf(a0.y);
            af[2] = f2bf(a0.z); af[3] = f2bf(a0.w);
            af[4] = f2bf(a1.x); af[5] = f2bf(a1.y);
            af[6] = f2bf(a1.z); af[7] = f2bf(a1.w);
#pragma unroll
            for (int cb = 0; cb < 8; ++cb) {
                bf8v b = *reinterpret_cast<const bf8v*>(
                             WpP + (size_t)((q * 8 + cb) * 64 + l) * 8);
                acc[cb] = __builtin_amdgcn_mfma_f32_16x16x32_bf16(af, b, acc[cb], 0, 0, 0);
            }
        }
    }
#undef STAGE64

    // epilogue: bias, norms (reduce across 16 lanes sharing a C-row), pack
    float bpv[8];
#pragma unroll
    for (int cb = 0; cb < 8; ++cb) bpv[cb] = bp[cb * 16 + li];
#pragma unroll
    for (int cb = 0; cb < 8; ++cb)
#pragma unroll
        for (int r = 0; r < 4; ++r) acc[cb][r] += bpv[cb];

#pragma unroll
    for (int r = 0; r < 4; ++r) {
        float s = 0.f;
#pragma unroll
        for (int cb = 0; cb < 8; ++cb) {
            float v = acc[cb][r];
            s += v * v;
        }
        s += __shfl_xor(s, 1);
        s += __shfl_xor(s, 2);
        s += __shfl_xor(s, 4);
        s += __shfl_xor(s, 8);
        int grow = rowblk + w * 16 + 4 * g + r;
        if (li == 0) normv[grow] = (grow < Mreal) ? s : 1e30f;
    }

#pragma unroll
    for (int cb = 0; cb < 8; ++cb) {
        int d = cb * 16 + li;
        int q = d >> 5, g2 = (d & 31) >> 3, j = d & 7;
#pragma unroll
        for (int r = 0; r < 4; ++r) {
            int grow = rowblk + w * 16 + 4 * g + r;
            float v = (grow < Mreal) ? acc[cb][r] : 0.f;
            size_t e = ((size_t)((grow >> 4) * 4 + q) * 64 +
                        (g2 * 16 + (grow & 15))) * 8 + j;
            outP[e] = f2bf(v);
        }
    }
}

// ---------------------------------------------------------------------------
// Kernel 2: lab[i] = stable descending rank of SorP_train[i, Y[i]]
// ---------------------------------------------------------------------------
__global__ __launch_bounds__(256) void k_labels(const float* __restrict__ S,
                                                const int* __restrict__ Y,
                                                int* __restrict__ lab) {
    int w = threadIdx.x >> 6, l = threadIdx.x & 63;
    int i = blockIdx.x * 4 + w;
    if (i >= NPAD) return;
    int cnt = 0;
    if (i < NTRAIN) {
        int y = Y[i];
        float t = S[(size_t)i * NCLS + y];
        float v1 = S[(size_t)i * NCLS + l];
        bool p1 = (v1 > t) || (v1 == t && l < y);
        unsigned long long b1 = __ballot(p1);
        bool p2 = false;
        if (l < NCLS - 64) {
            float v2 = S[(size_t)i * NCLS + 64 + l];
            p2 = (v2 > t) || (v2 == t && (64 + l) < y);
        }
        unsigned long long b2 = __ballot(p2);
        cnt = __popcll(b1) + __popcll(b2);
    }
    if (l == 0) lab[i] = cnt;
}

// ---------------------------------------------------------------------------
// Kernel 4: main fused kernel. Grid (NCH, 8): ch = blockIdx.x (XCD = ch%8),
// bt = blockIdx.y. Per i-tile: S = px @ pX^T via MFMA (B-frags double-buffered
// across unrolled ib; kn/lab prefetched per tile), Kis = exp(-(qn+kn-2dot)/256),
// drop-self, fixed-point ds_add_u32 bins by lab[i]; plain stores to partials.
// ---------------------------------------------------------------------------
__global__ __launch_bounds__(256) void k_main(const short* __restrict__ pxp,
                                              const short* __restrict__ pXp,
                                              const float* __restrict__ qn,
                                              const float* __restrict__ kn,
                                              const int* __restrict__ lab,
                                              float* __restrict__ part,
                                              int NCH) {
    __shared__ __align__(16) unsigned plds[128 * PSTRIDE];   // u32 fixed-point bins
    const int tid = threadIdx.x;
    const int w = tid >> 6, l = tid & 63, g = l >> 4, li = l & 15;
    const int ch = blockIdx.x;
    const int bt = blockIdx.y;       // 0..7

    for (int s = tid; s < 128 * PSTRIDE; s += 256) plds[s] = 0u;
    __syncthreads();                 // only barrier in the kernel

    bf8v af[2][4];                   // px A-frags, persistent
#pragma unroll
    for (int rb = 0; rb < 2; ++rb)
#pragma unroll
        for (int q = 0; q < 4; ++q) {
            int RB = bt * 8 + w * 2 + rb;
            af[rb][q] = *reinterpret_cast<const bf8v*>(
                            pxp + (size_t)((RB * 4 + q) * 64 + l) * 8);
        }
    float qnv[2][4];
#pragma unroll
    for (int rb = 0; rb < 2; ++rb)
#pragma unroll
        for (int r = 0; r < 4; ++r)
            qnv[rb][r] = qn[bt * 128 + w * 32 + rb * 16 + 4 * g + r];

#pragma unroll 1
    for (int t = ch; t < NTILES; t += NCH) {
        const int i0 = t * 128;
        // prefetch the whole tile's kn/lab (per-lane: 8 values each)
        float knv8[8];
        int   labv8[8];
#pragma unroll
        for (int ib = 0; ib < 8; ++ib) {
            knv8[ib]  = kn[i0 + ib * 16 + li];
            labv8[ib] = lab[i0 + ib * 16 + li];
        }
        // double-buffered B-frag pipeline across fully-unrolled ib
        bf8v bfr2[2][4];
        {
            const int RBi = (i0 >> 4);
#pragma unroll
            for (int q = 0; q < 4; ++q)
                bfr2[0][q] = *reinterpret_cast<const bf8v*>(
                                 pXp + (size_t)((RBi * 4 + q) * 64 + l) * 8);
        }
#pragma unroll
        for (int ib = 0; ib < 8; ++ib) {
            if (ib < 7) {                         // prefetch next sub-tile
                const int RBn = (i0 >> 4) + ib + 1;
#pragma unroll
                for (int q = 0; q < 4; ++q)
                    bfr2[(ib + 1) & 1][q] = *reinterpret_cast<const bf8v*>(
                        pXp + (size_t)((RBn * 4 + q) * 64 + l) * 8);
            }
            f32x4 s0 = (f32x4){0.f, 0.f, 0.f, 0.f};
            f32x4 s1 = (f32x4){0.f, 0.f, 0.f, 0.f};
#pragma unroll
            for (int q = 0; q < 4; ++q) {
                s0 = __builtin_amdgcn_mfma_f32_16x16x32_bf16(af[0][q], bfr2[ib & 1][q], s0, 0, 0, 0);
                s1 = __builtin_amdgcn_mfma_f32_16x16x32_bf16(af[1][q], bfr2[ib & 1][q], s1, 0, 0, 0);
            }
            const float knv  = knv8[ib];
            const int   labv = labv8[ib];
#pragma unroll
            for (int rb = 0; rb < 2; ++rb) {
                f32x4 sv = rb ? s1 : s0;
#pragma unroll
                for (int r = 0; r < 4; ++r) {
                    float sqd = qnv[rb][r] + knv - 2.f * sv[r];
                    float kis = __expf(sqd * (-1.f / 256.f));
                    kis = (kis < 1.0f) ? kis : 0.f;   // drop_self (1-1e-10 == 1.0f)
                    unsigned qv = (unsigned)__float2uint_rn(kis * FIXS);
                    int rowl = w * 32 + rb * 16 + 4 * g + r;
                    atomicAdd(&plds[rowl * PSTRIDE + labv], qv);   // ds_add_u32
                }
            }
        }
    }

    // epilogue: each wave flushes its own rows with plain vectorized stores
#pragma unroll 1
    for (int rr = 0; rr < 32; ++rr) {
        int row = w * 32 + rr;
        if (l < PCOLS / 2) {
            uint2 u = *reinterpret_cast<const uint2*>(&plds[row * PSTRIDE + l * 2]);
            float2 v = make_float2((float)u.x * FIXI, (float)u.y * FIXI);
            int grow = bt * 128 + row;
            *reinterpret_cast<float2*>(
                &part[((size_t)grow * NCH + ch) * PCOLS + l * 2]) = v;
        }
    }
}

// ---------------------------------------------------------------------------
// Kernel 5: fused reduce + normalize + rank-gather.
// Block b: pr[c] = sum_ch part[b][ch][c]; out[b,c] = pr[rank_q(b,c)] / sum.
// ---------------------------------------------------------------------------
__global__ __launch_bounds__(128) void k_final(const float* __restrict__ part,
                                               const float* __restrict__ SorPq,
                                               float* __restrict__ out,
                                               int NCH) {
    __shared__ float sp[NCLS];
    __shared__ float pr[PCOLS];
    int b = blockIdx.x, c = threadIdx.x;
    if (c < NCLS) sp[c] = SorPq[(size_t)b * NCLS + c];
    if (c < PCOLS) {
        float s = 0.f;
        const float* p = part + (size_t)b * NCH * PCOLS + c;
        for (int ch = 0; ch < NCH; ++ch) s += p[(size_t)ch * PCOLS];
        pr[c] = s;
    }
    __syncthreads();
    float tot = 0.f;
    for (int k = 0; k < NCLS; ++k) tot += pr[k];   // broadcast reads, deterministic
    if (c < NCLS) {
        float s = sp[c];
        int r = 0;
        for (int k = 0; k < NCLS; ++k) {
            float sk = sp[k];
            r += (sk > s || (sk == s && k < c)) ? 1 : 0;
        }
        out[(size_t)b * NCLS + c] = pr[r] / tot;
    }
}

// ---------------------------------------------------------------------------
extern "C" void kernel_launch(void* const* d_in, const int* in_sizes, int n_in,
                              void* d_out, int out_size, void* d_ws, size_t ws_size,
                              hipStream_t stream) {
    const float* x    = (const float*)d_in[0];   // [1024,768]
    const float* X    = (const float*)d_in[1];   // [50000,768]
    const float* Wp   = (const float*)d_in[2];   // [768,128]
    const float* bp   = (const float*)d_in[3];   // [128]
    const int*   Y    = (const int*)  d_in[4];   // [50000]
    const float* SPt  = (const float*)d_in[5];   // [50000,100]
    const float* SPq  = (const float*)d_in[6];   // [1024,100]
    float* out = (float*)d_out;                  // [1024,100]

    char* ws = (char*)d_ws;
    // ws layout (bytes), all 16B-aligned
    short* WpP = (short*)(ws + 0);                       //   196,608
    short* pXp = (short*)(ws + 196608);                  // 12,812,288
    short* pxq = (short*)(ws + 13008896);                //    262,144
    float* kn  = (float*)(ws + 13271040);                //    200,192
    float* qn  = (float*)(ws + 13471232);                //      4,096
    int*   lab = (int*)  (ws + 13475328);                //    200,192
    float* part= (float*)(ws + 13675520);                // NCH*1024*104*4

    // choose NCH (chunk count): 96 -> 768 blocks (3/CU), multiple of 8 so
    // XCD = linear_id % 8 = ch % 8 (b-tiles sharing pX tiles co-locate).
    const size_t base = 13675520;
    const size_t per  = (size_t)BQ * PCOLS * 4;   // bytes per chunk slice
    int NCH = 96;
    if (ws_size > base) {
        size_t fit = (ws_size - base) / per;
        if ((size_t)NCH > fit) NCH = (int)fit;
    } else {
        NCH = 8;
    }
    NCH &= ~7;                  // multiple of 8
    if (NCH < 8) NCH = 8;

    k_pack_wp<<<48, 256, 0, stream>>>(Wp, WpP);
    k_proj<<<NPAD / 64, 256, 0, stream>>>(X, WpP, bp, pXp, kn, NTRAIN);
    k_proj<<<(BQ + 63) / 64, 256, 0, stream>>>(x, WpP, bp, pxq, qn, BQ);
    k_labels<<<(NPAD + 3) / 4, 256, 0, stream>>>(SPt, Y, lab);
    k_main<<<dim3(NCH, 8), 256, 0, stream>>>(pxq, pXp, qn, kn, lab, part, NCH);
    k_final<<<BQ, 128, 0, stream>>>(part, SPq, out, NCH);
}

// Round 11
// 142.191 us; speedup vs baseline: 1.2712x; 1.2712x over previous
//
#include <hip/hip_runtime.h>

// ---------------------------------------------------------------------------
// KernelClassifier: px = x@Wp+bp; pX = X@Wp+bp; Kis = exp(-||px-pX||^2/256)
// (drop self: Kis<1.0f), pred[b,lab[i]] += Kis[b,i], normalize, rank-gather.
// R4: fp32 LDS atomicAdd was a CAS loop -> fixed-point ds_add_u32 (451->216us).
// R5-R10: three different k_proj load structures all ~90us, all pipes idle.
//     Common factor: 16 WpP B-frag global loads consumed in-iteration
//     (compiler waitcnt exposes L2 latency every iter) + vmcnt(0) full drain.
// R11: per-wave software pipeline with counted vmcnt. B(kb) in dbuf REGISTERS
//     issued 1 iter early; A staged 2 iters early (R10's LDS path); steady
//     iter: issueB(kb+1) -> vmcnt(20) -> ds_read A -> lgkm0+schedbar ->
//     stage(kb+2) -> MFMA (no in-iter memory waits).
// ---------------------------------------------------------------------------

typedef short  bf8v  __attribute__((ext_vector_type(8)));   // 8 x bf16 (4 VGPR)
typedef float  f32x4 __attribute__((ext_vector_type(4)));   // MFMA C/D

#define NTRAIN 50000
#define NPAD   50048          // 391 * 128
#define NTILES 391
#define BQ     1024
#define DIN    768
#define DP     128
#define NCLS   100
#define PSTRIDE 104           // LDS pred row stride (u32); 128*104*4=53248B
#define PCOLS  104            // partial row width (>=100, float2-aligned)
#define FIXS   2097152.0f     // 2^21 fixed-point scale
#define FIXI   (1.0f / 2097152.0f)

__device__ __forceinline__ short f2bf(float x) {   // fp32 -> bf16 RNE
    unsigned u = __float_as_uint(x);
    u += 0x7FFFu + ((u >> 16) & 1u);
    return (short)(u >> 16);
}

// global_load_lds pointer casts
#define AS1U(p) ((const __attribute__((address_space(1))) unsigned int*)(unsigned long long)(p))
#define AS3U(p) ((__attribute__((address_space(3))) unsigned int*)(unsigned int)(unsigned long long)(p))

// ---------------------------------------------------------------------------
// Kernel 0: pack Wp into B-fragment order: WpP[q][cb][lane][j] =
//   bf16(Wp[32q + 8*(lane>>4) + j][16cb + (lane&15)])
// ---------------------------------------------------------------------------
__global__ __launch_bounds__(256) void k_pack_wp(const float* __restrict__ Wp,
                                                 short* __restrict__ WpP) {
    int tid = blockIdx.x * 256 + threadIdx.x;
    if (tid >= 24 * 8 * 64) return;
    int l = tid & 63, cb = (tid >> 6) & 7, q = tid >> 9;
    int c = cb * 16 + (l & 15);
    int g = l >> 4;
    bf8v o;
#pragma unroll
    for (int j = 0; j < 8; ++j) {
        int k = q * 32 + g * 8 + j;
        o[j] = f2bf(Wp[k * DP + c]);
    }
    *reinterpret_cast<bf8v*>(WpP + (size_t)tid * 8) = o;
}

// ---------------------------------------------------------------------------
// Kernel 1: projection GEMM  out = rows @ Wp + bp   (K=768, Ncols=128)
// BM=64, 4 waves, barrier-free, per-wave SW pipeline with counted vmcnt.
// ---------------------------------------------------------------------------
__global__ __launch_bounds__(256) void k_proj(const float* __restrict__ Xin,
                                              const short* __restrict__ WpP,
                                              const float* __restrict__ bp,
                                              short* __restrict__ outP,
                                              float* __restrict__ normv,
                                              int Mreal) {
    __shared__ __align__(16) float Xlds[2][64 * 64];   // 2 x 16 KB fp32 tiles
    const int tid = threadIdx.x;
    const int w = tid >> 6, l = tid & 63, g = l >> 4, li = l & 15;
    const int rowblk = blockIdx.x * 64;

    f32x4 acc[8];
#pragma unroll
    for (int cb = 0; cb < 8; ++cb) acc[cb] = (f32x4){0.f, 0.f, 0.f, 0.f};

    // stage wave w's 16x64 fp32 quarter of K-tile kb (linear LDS dest,
    // inverse-swizzled global source; paired with swizzled ds_read)
#define STAGE64(lbuf, kb)                                                     \
    {                                                                         \
        _Pragma("unroll")                                                     \
        for (int it = 0; it < 4; ++it) {                                      \
            int s  = w * 256 + it * 64 + l;                                   \
            int r  = s >> 4;                                                  \
            int c4 = (s & 15) ^ (r & 7);                                      \
            int rg = rowblk + r;                                              \
            rg = (rg < Mreal) ? rg : (Mreal - 1);                             \
            const float* gp = Xin + (size_t)rg * DIN + (kb) * 64 + c4 * 4;    \
            const float* lp = (lbuf) + (w * 256 + it * 64) * 4;               \
            __builtin_amdgcn_global_load_lds(AS1U(gp), AS3U(lp), 16, 0, 0);   \
        }                                                                     \
    }
    // issue the 16 B-frags of K-tile kb into a register set
#define ISSUE_B(dst, kb)                                                      \
    {                                                                         \
        _Pragma("unroll")                                                     \
        for (int f = 0; f < 16; ++f)                                          \
            dst[f] = *reinterpret_cast<const bf8v*>(                          \
                WpP + ((size_t)((kb) * 16 + f) * 64 + l) * 8);                \
    }
    // read this wave's A-frags (4x ds_read_b128, swizzled slots)
#define READ_A(avec, lbuf)                                                    \
    {                                                                         \
        const float* rbase = (lbuf) + (w * 16 + li) * 64;                     \
        _Pragma("unroll")                                                     \
        for (int kc = 0; kc < 2; ++kc) {                                      \
            int s0 = (kc * 8 + g * 2)     ^ (li & 7);                         \
            int s1 = (kc * 8 + g * 2 + 1) ^ (li & 7);                         \
            avec[kc * 2]     = *reinterpret_cast<const float4*>(rbase + s0 * 4); \
            avec[kc * 2 + 1] = *reinterpret_cast<const float4*>(rbase + s1 * 4); \
        }                                                                     \
    }
#define COMPUTE(breg, avec)                                                   \
    {                                                                         \
        _Pragma("unroll")                                                     \
        for (int kc = 0; kc < 2; ++kc) {                                      \
            float4 a0 = avec[kc * 2], a1 = avec[kc * 2 + 1];                  \
            bf8v af;                                                          \
            af[0] = f2bf(a0.x); af[1] = f2bf(a0.y);                           \
            af[2] = f2bf(a0.z); af[3] = f2bf(a0.w);                           \
            af[4] = f2bf(a1.x); af[5] = f2bf(a1.y);                           \
            af[6] = f2bf(a1.z); af[7] = f2bf(a1.w);                           \
            _Pragma("unroll")                                                 \
            for (int cb = 0; cb < 8; ++cb)                                    \
                acc[cb] = __builtin_amdgcn_mfma_f32_16x16x32_bf16(            \
                              af, breg[kc * 8 + cb], acc[cb], 0, 0, 0);       \
        }                                                                     \
    }
#define WAITV20 asm volatile("s_waitcnt vmcnt(20)" ::: "memory")
#define WAITL0  asm volatile("s_waitcnt lgkmcnt(0)" ::: "memory")

    bf8v breg0[16], breg1[16];
    float4 a[4];

    // prologue: A(0), B(0), A(1) in flight (24 VMEM instrs)
    STAGE64(&Xlds[0][0], 0);
    ISSUE_B(breg0, 0);
    STAGE64(&Xlds[1][0], 1);

#pragma unroll 1
    for (int kb = 0; kb < 12; kb += 2) {
        // even phase: consume A(kb)/B(kb); keep B(kb+1)+stage(kb+1) in flight
        if (kb + 1 < 12) ISSUE_B(breg1, kb + 1);
        WAITV20;                              // A(kb), B(kb) complete
        READ_A(a, &Xlds[0][0]);
        WAITL0;                               // reads retired before overwrite
        __builtin_amdgcn_sched_barrier(0);
        if (kb + 2 < 12) STAGE64(&Xlds[0][0], kb + 2);
        COMPUTE(breg0, a);

        // odd phase: consume A(kb+1)/B(kb+1)
        if (kb + 2 < 12) ISSUE_B(breg0, kb + 2);
        WAITV20;                              // A(kb+1), B(kb+1) complete
        READ_A(a, &Xlds[1][0]);
        WAITL0;
        __builtin_amdgcn_sched_barrier(0);
        if (kb + 3 < 12) STAGE64(&Xlds[1][0], kb + 3);
        COMPUTE(breg1, a);
    }
#undef STAGE64
#undef ISSUE_B
#undef READ_A
#undef COMPUTE
#undef WAITV20
#undef WAITL0

    // epilogue: bias, norms (reduce across 16 lanes sharing a C-row), pack
    float bpv[8];
#pragma unroll
    for (int cb = 0; cb < 8; ++cb) bpv[cb] = bp[cb * 16 + li];
#pragma unroll
    for (int cb = 0; cb < 8; ++cb)
#pragma unroll
        for (int r = 0; r < 4; ++r) acc[cb][r] += bpv[cb];

#pragma unroll
    for (int r = 0; r < 4; ++r) {
        float s = 0.f;
#pragma unroll
        for (int cb = 0; cb < 8; ++cb) {
            float v = acc[cb][r];
            s += v * v;
        }
        s += __shfl_xor(s, 1);
        s += __shfl_xor(s, 2);
        s += __shfl_xor(s, 4);
        s += __shfl_xor(s, 8);
        int grow = rowblk + w * 16 + 4 * g + r;
        if (li == 0) normv[grow] = (grow < Mreal) ? s : 1e30f;
    }

#pragma unroll
    for (int cb = 0; cb < 8; ++cb) {
        int d = cb * 16 + li;
        int q = d >> 5, g2 = (d & 31) >> 3, j = d & 7;
#pragma unroll
        for (int r = 0; r < 4; ++r) {
            int grow = rowblk + w * 16 + 4 * g + r;
            float v = (grow < Mreal) ? acc[cb][r] : 0.f;
            size_t e = ((size_t)((grow >> 4) * 4 + q) * 64 +
                        (g2 * 16 + (grow & 15))) * 8 + j;
            outP[e] = f2bf(v);
        }
    }
}

// ---------------------------------------------------------------------------
// Kernel 2: lab[i] = stable descending rank of SorP_train[i, Y[i]]
// ---------------------------------------------------------------------------
__global__ __launch_bounds__(256) void k_labels(const float* __restrict__ S,
                                                const int* __restrict__ Y,
                                                int* __restrict__ lab) {
    int w = threadIdx.x >> 6, l = threadIdx.x & 63;
    int i = blockIdx.x * 4 + w;
    if (i >= NPAD) return;
    int cnt = 0;
    if (i < NTRAIN) {
        int y = Y[i];
        float t = S[(size_t)i * NCLS + y];
        float v1 = S[(size_t)i * NCLS + l];
        bool p1 = (v1 > t) || (v1 == t && l < y);
        unsigned long long b1 = __ballot(p1);
        bool p2 = false;
        if (l < NCLS - 64) {
            float v2 = S[(size_t)i * NCLS + 64 + l];
            p2 = (v2 > t) || (v2 == t && (64 + l) < y);
        }
        unsigned long long b2 = __ballot(p2);
        cnt = __popcll(b1) + __popcll(b2);
    }
    if (l == 0) lab[i] = cnt;
}

// ---------------------------------------------------------------------------
// Kernel 4: main fused kernel. Grid (NCH, 8): ch = blockIdx.x (XCD = ch%8),
// bt = blockIdx.y. Per i-tile: S = px @ pX^T via MFMA (B-frags double-buffered
// across unrolled ib; kn/lab prefetched per tile), Kis = exp(-(qn+kn-2dot)/256),
// drop-self, fixed-point ds_add_u32 bins by lab[i]; plain stores to partials.
// ---------------------------------------------------------------------------
__global__ __launch_bounds__(256) void k_main(const short* __restrict__ pxp,
                                              const short* __restrict__ pXp,
                                              const float* __restrict__ qn,
                                              const float* __restrict__ kn,
                                              const int* __restrict__ lab,
                                              float* __restrict__ part,
                                              int NCH) {
    __shared__ __align__(16) unsigned plds[128 * PSTRIDE];   // u32 fixed-point bins
    const int tid = threadIdx.x;
    const int w = tid >> 6, l = tid & 63, g = l >> 4, li = l & 15;
    const int ch = blockIdx.x;
    const int bt = blockIdx.y;       // 0..7

    for (int s = tid; s < 128 * PSTRIDE; s += 256) plds[s] = 0u;
    __syncthreads();                 // only barrier in the kernel

    bf8v af[2][4];                   // px A-frags, persistent
#pragma unroll
    for (int rb = 0; rb < 2; ++rb)
#pragma unroll
        for (int q = 0; q < 4; ++q) {
            int RB = bt * 8 + w * 2 + rb;
            af[rb][q] = *reinterpret_cast<const bf8v*>(
                            pxp + (size_t)((RB * 4 + q) * 64 + l) * 8);
        }
    float qnv[2][4];
#pragma unroll
    for (int rb = 0; rb < 2; ++rb)
#pragma unroll
        for (int r = 0; r < 4; ++r)
            qnv[rb][r] = qn[bt * 128 + w * 32 + rb * 16 + 4 * g + r];

#pragma unroll 1
    for (int t = ch; t < NTILES; t += NCH) {
        const int i0 = t * 128;
        // prefetch the whole tile's kn/lab (per-lane: 8 values each)
        float knv8[8];
        int   labv8[8];
#pragma unroll
        for (int ib = 0; ib < 8; ++ib) {
            knv8[ib]  = kn[i0 + ib * 16 + li];
            labv8[ib] = lab[i0 + ib * 16 + li];
        }
        // double-buffered B-frag pipeline across fully-unrolled ib
        bf8v bfr2[2][4];
        {
            const int RBi = (i0 >> 4);
#pragma unroll
            for (int q = 0; q < 4; ++q)
                bfr2[0][q] = *reinterpret_cast<const bf8v*>(
                                 pXp + (size_t)((RBi * 4 + q) * 64 + l) * 8);
        }
#pragma unroll
        for (int ib = 0; ib < 8; ++ib) {
            if (ib < 7) {                         // prefetch next sub-tile
                const int RBn = (i0 >> 4) + ib + 1;
#pragma unroll
                for (int q = 0; q < 4; ++q)
                    bfr2[(ib + 1) & 1][q] = *reinterpret_cast<const bf8v*>(
                        pXp + (size_t)((RBn * 4 + q) * 64 + l) * 8);
            }
            f32x4 s0 = (f32x4){0.f, 0.f, 0.f, 0.f};
            f32x4 s1 = (f32x4){0.f, 0.f, 0.f, 0.f};
#pragma unroll
            for (int q = 0; q < 4; ++q) {
                s0 = __builtin_amdgcn_mfma_f32_16x16x32_bf16(af[0][q], bfr2[ib & 1][q], s0, 0, 0, 0);
                s1 = __builtin_amdgcn_mfma_f32_16x16x32_bf16(af[1][q], bfr2[ib & 1][q], s1, 0, 0, 0);
            }
            const float knv  = knv8[ib];
            const int   labv = labv8[ib];
#pragma unroll
            for (int rb = 0; rb < 2; ++rb) {
                f32x4 sv = rb ? s1 : s0;
#pragma unroll
                for (int r = 0; r < 4; ++r) {
                    float sqd = qnv[rb][r] + knv - 2.f * sv[r];
                    float kis = __expf(sqd * (-1.f / 256.f));
                    kis = (kis < 1.0f) ? kis : 0.f;   // drop_self (1-1e-10 == 1.0f)
                    unsigned qv = (unsigned)__float2uint_rn(kis * FIXS);
                    int rowl = w * 32 + rb * 16 + 4 * g + r;
                    atomicAdd(&plds[rowl * PSTRIDE + labv], qv);   // ds_add_u32
                }
            }
        }
    }

    // epilogue: each wave flushes its own rows with plain vectorized stores
#pragma unroll 1
    for (int rr = 0; rr < 32; ++rr) {
        int row = w * 32 + rr;
        if (l < PCOLS / 2) {
            uint2 u = *reinterpret_cast<const uint2*>(&plds[row * PSTRIDE + l * 2]);
            float2 v = make_float2((float)u.x * FIXI, (float)u.y * FIXI);
            int grow = bt * 128 + row;
            *reinterpret_cast<float2*>(
                &part[((size_t)grow * NCH + ch) * PCOLS + l * 2]) = v;
        }
    }
}

// ---------------------------------------------------------------------------
// Kernel 5: fused reduce + normalize + rank-gather.
// ---------------------------------------------------------------------------
__global__ __launch_bounds__(128) void k_final(const float* __restrict__ part,
                                               const float* __restrict__ SorPq,
                                               float* __restrict__ out,
                                               int NCH) {
    __shared__ float sp[NCLS];
    __shared__ float pr[PCOLS];
    int b = blockIdx.x, c = threadIdx.x;
    if (c < NCLS) sp[c] = SorPq[(size_t)b * NCLS + c];
    if (c < PCOLS) {
        float s = 0.f;
        const float* p = part + (size_t)b * NCH * PCOLS + c;
        for (int ch = 0; ch < NCH; ++ch) s += p[(size_t)ch * PCOLS];
        pr[c] = s;
    }
    __syncthreads();
    float tot = 0.f;
    for (int k = 0; k < NCLS; ++k) tot += pr[k];   // broadcast reads, deterministic
    if (c < NCLS) {
        float s = sp[c];
        int r = 0;
        for (int k = 0; k < NCLS; ++k) {
            float sk = sp[k];
            r += (sk > s || (sk == s && k < c)) ? 1 : 0;
        }
        out[(size_t)b * NCLS + c] = pr[r] / tot;
    }
}

// ---------------------------------------------------------------------------
extern "C" void kernel_launch(void* const* d_in, const int* in_sizes, int n_in,
                              void* d_out, int out_size, void* d_ws, size_t ws_size,
                              hipStream_t stream) {
    const float* x    = (const float*)d_in[0];   // [1024,768]
    const float* X    = (const float*)d_in[1];   // [50000,768]
    const float* Wp   = (const float*)d_in[2];   // [768,128]
    const float* bp   = (const float*)d_in[3];   // [128]
    const int*   Y    = (const int*)  d_in[4];   // [50000]
    const float* SPt  = (const float*)d_in[5];   // [50000,100]
    const float* SPq  = (const float*)d_in[6];   // [1024,100]
    float* out = (float*)d_out;                  // [1024,100]

    char* ws = (char*)d_ws;
    // ws layout (bytes), all 16B-aligned
    short* WpP = (short*)(ws + 0);                       //   196,608
    short* pXp = (short*)(ws + 196608);                  // 12,812,288
    short* pxq = (short*)(ws + 13008896);                //    262,144
    float* kn  = (float*)(ws + 13271040);                //    200,192
    float* qn  = (float*)(ws + 13471232);                //      4,096
    int*   lab = (int*)  (ws + 13475328);                //    200,192
    float* part= (float*)(ws + 13675520);                // NCH*1024*104*4

    // choose NCH (chunk count): 96 -> 768 blocks (3/CU), multiple of 8 so
    // XCD = linear_id % 8 = ch % 8 (b-tiles sharing pX tiles co-locate).
    const size_t base = 13675520;
    const size_t per  = (size_t)BQ * PCOLS * 4;   // bytes per chunk slice
    int NCH = 96;
    if (ws_size > base) {
        size_t fit = (ws_size - base) / per;
        if ((size_t)NCH > fit) NCH = (int)fit;
    } else {
        NCH = 8;
    }
    NCH &= ~7;                  // multiple of 8
    if (NCH < 8) NCH = 8;

    k_pack_wp<<<48, 256, 0, stream>>>(Wp, WpP);
    k_proj<<<NPAD / 64, 256, 0, stream>>>(X, WpP, bp, pXp, kn, NTRAIN);
    k_proj<<<(BQ + 63) / 64, 256, 0, stream>>>(x, WpP, bp, pxq, qn, BQ);
    k_labels<<<(NPAD + 3) / 4, 256, 0, stream>>>(SPt, Y, lab);
    k_main<<<dim3(NCH, 8), 256, 0, stream>>>(pxq, pXp, qn, kn, lab, part, NCH);
    k_final<<<BQ, 128, 0, stream>>>(part, SPq, out, NCH);
}

// Round 12
// 124.321 us; speedup vs baseline: 1.4539x; 1.1437x over previous
//
#include <hip/hip_runtime.h>

// ---------------------------------------------------------------------------
// KernelClassifier: px = x@Wp+bp; pX = X@Wp+bp; Kis = exp(-||px-pX||^2/256)
// (drop self: Kis<1.0f), pred[b,lab[i]] += Kis[b,i], normalize, rank-gather.
// R4: fp32 LDS atomicAdd was a CAS loop -> fixed-point ds_add_u32 (451->216us).
// R11: per-wave counted-vmcnt pipeline (B 1 iter early in regs, A 2 early in
//     LDS) broke the ~90us k_proj wall; total 180->142.
// R12: (a) k_proj single-buffer B + dual waits vmcnt(20)/vmcnt(4),
//     __launch_bounds__(256,3) -> 3 waves/SIMD (was 2 at 205 VGPR);
//     (b) k_final 256thr 2-way split reduction; (c) merge pack_wp+labels.
// ---------------------------------------------------------------------------

typedef short  bf8v  __attribute__((ext_vector_type(8)));   // 8 x bf16 (4 VGPR)
typedef float  f32x4 __attribute__((ext_vector_type(4)));   // MFMA C/D

#define NTRAIN 50000
#define NPAD   50048          // 391 * 128
#define NTILES 391
#define BQ     1024
#define DIN    768
#define DP     128
#define NCLS   100
#define PSTRIDE 104           // LDS pred row stride (u32); 128*104*4=53248B
#define PCOLS  104            // partial row width (>=100, float2-aligned)
#define FIXS   2097152.0f     // 2^21 fixed-point scale
#define FIXI   (1.0f / 2097152.0f)

__device__ __forceinline__ short f2bf(float x) {   // fp32 -> bf16 RNE
    unsigned u = __float_as_uint(x);
    u += 0x7FFFu + ((u >> 16) & 1u);
    return (short)(u >> 16);
}

// global_load_lds pointer casts
#define AS1U(p) ((const __attribute__((address_space(1))) unsigned int*)(unsigned long long)(p))
#define AS3U(p) ((__attribute__((address_space(3))) unsigned int*)(unsigned int)(unsigned long long)(p))

// ---------------------------------------------------------------------------
// Kernel 0: fused prep. Blocks [0,48): pack Wp into B-fragment order.
// Blocks [48,..): lab[i] = stable descending rank of SorP_train[i, Y[i]].
// ---------------------------------------------------------------------------
__global__ __launch_bounds__(256) void k_prep(const float* __restrict__ Wp,
                                              short* __restrict__ WpP,
                                              const float* __restrict__ S,
                                              const int* __restrict__ Y,
                                              int* __restrict__ lab) {
    if (blockIdx.x < 48) {
        int tid = blockIdx.x * 256 + threadIdx.x;
        if (tid >= 24 * 8 * 64) return;
        int l = tid & 63, cb = (tid >> 6) & 7, q = tid >> 9;
        int c = cb * 16 + (l & 15);
        int g = l >> 4;
        bf8v o;
#pragma unroll
        for (int j = 0; j < 8; ++j) {
            int k = q * 32 + g * 8 + j;
            o[j] = f2bf(Wp[k * DP + c]);
        }
        *reinterpret_cast<bf8v*>(WpP + (size_t)tid * 8) = o;
        return;
    }
    int w = threadIdx.x >> 6, l = threadIdx.x & 63;
    int i = (blockIdx.x - 48) * 4 + w;
    if (i >= NPAD) return;
    int cnt = 0;
    if (i < NTRAIN) {
        int y = Y[i];
        float t = S[(size_t)i * NCLS + y];
        float v1 = S[(size_t)i * NCLS + l];
        bool p1 = (v1 > t) || (v1 == t && l < y);
        unsigned long long b1 = __ballot(p1);
        bool p2 = false;
        if (l < NCLS - 64) {
            float v2 = S[(size_t)i * NCLS + 64 + l];
            p2 = (v2 > t) || (v2 == t && (64 + l) < y);
        }
        unsigned long long b2 = __ballot(p2);
        cnt = __popcll(b1) + __popcll(b2);
    }
    if (l == 0) lab[i] = cnt;
}

// ---------------------------------------------------------------------------
// Kernel 1: projection GEMM  out = rows @ Wp + bp   (K=768, Ncols=128)
// BM=64, 4 waves, barrier-free per-wave pipeline, single-buffer B regs.
// Phase kb: vmcnt(20) [A(kb) done; stage(kb+1)+B(kb) stay in flight] ->
// ds_read A -> lgkm0 -> stage(kb+2) -> vmcnt(4) [B(kb) done; stage(kb+2)
// in flight] -> 16 MFMA -> issue B(kb+1) into the same reg set.
// ---------------------------------------------------------------------------
__global__ __launch_bounds__(256, 3) void k_proj(const float* __restrict__ Xin,
                                                 const short* __restrict__ WpP,
                                                 const float* __restrict__ bp,
                                                 short* __restrict__ outP,
                                                 float* __restrict__ normv,
                                                 int Mreal) {
    __shared__ __align__(16) float Xlds[2][64 * 64];   // 2 x 16 KB fp32 tiles
    const int tid = threadIdx.x;
    const int w = tid >> 6, l = tid & 63, g = l >> 4, li = l & 15;
    const int rowblk = blockIdx.x * 64;

    f32x4 acc[8];
#pragma unroll
    for (int cb = 0; cb < 8; ++cb) acc[cb] = (f32x4){0.f, 0.f, 0.f, 0.f};

#define STAGE64(lbuf, kb)                                                     \
    {                                                                         \
        _Pragma("unroll")                                                     \
        for (int it = 0; it < 4; ++it) {                                      \
            int s  = w * 256 + it * 64 + l;                                   \
            int r  = s >> 4;                                                  \
            int c4 = (s & 15) ^ (r & 7);                                      \
            int rg = rowblk + r;                                              \
            rg = (rg < Mreal) ? rg : (Mreal - 1);                             \
            const float* gp = Xin + (size_t)rg * DIN + (kb) * 64 + c4 * 4;    \
            const float* lp = (lbuf) + (w * 256 + it * 64) * 4;               \
            __builtin_amdgcn_global_load_lds(AS1U(gp), AS3U(lp), 16, 0, 0);   \
        }                                                                     \
    }
#define ISSUE_B(dst, kb)                                                      \
    {                                                                         \
        _Pragma("unroll")                                                     \
        for (int f = 0; f < 16; ++f)                                          \
            dst[f] = *reinterpret_cast<const bf8v*>(                          \
                WpP + ((size_t)((kb) * 16 + f) * 64 + l) * 8);                \
    }
#define READ_A(avec, lbuf)                                                    \
    {                                                                         \
        const float* rbase = (lbuf) + (w * 16 + li) * 64;                     \
        _Pragma("unroll")                                                     \
        for (int kc = 0; kc < 2; ++kc) {                                      \
            int s0 = (kc * 8 + g * 2)     ^ (li & 7);                         \
            int s1 = (kc * 8 + g * 2 + 1) ^ (li & 7);                         \
            avec[kc * 2]     = *reinterpret_cast<const float4*>(rbase + s0 * 4); \
            avec[kc * 2 + 1] = *reinterpret_cast<const float4*>(rbase + s1 * 4); \
        }                                                                     \
    }
#define COMPUTE(breg, avec)                                                   \
    {                                                                         \
        _Pragma("unroll")                                                     \
        for (int kc = 0; kc < 2; ++kc) {                                      \
            float4 a0 = avec[kc * 2], a1 = avec[kc * 2 + 1];                  \
            bf8v af;                                                          \
            af[0] = f2bf(a0.x); af[1] = f2bf(a0.y);                           \
            af[2] = f2bf(a0.z); af[3] = f2bf(a0.w);                           \
            af[4] = f2bf(a1.x); af[5] = f2bf(a1.y);                           \
            af[6] = f2bf(a1.z); af[7] = f2bf(a1.w);                           \
            _Pragma("unroll")                                                 \
            for (int cb = 0; cb < 8; ++cb)                                    \
                acc[cb] = __builtin_amdgcn_mfma_f32_16x16x32_bf16(            \
                              af, breg[kc * 8 + cb], acc[cb], 0, 0, 0);       \
        }                                                                     \
    }

    bf8v breg[16];
    float4 a[4];

    // prologue: A(0), A(1), B(0) in flight (24 VMEM instrs)
    STAGE64(&Xlds[0][0], 0);
    STAGE64(&Xlds[1][0], 1);
    ISSUE_B(breg, 0);

#pragma unroll 1
    for (int kb = 0; kb < 12; ++kb) {
        asm volatile("s_waitcnt vmcnt(20)" ::: "memory");   // A(kb) landed
        READ_A(a, &Xlds[kb & 1][0]);
        asm volatile("s_waitcnt lgkmcnt(0)" ::: "memory");  // reads retired
        __builtin_amdgcn_sched_barrier(0);
        if (kb + 2 < 12) {
            STAGE64(&Xlds[kb & 1][0], kb + 2);
            asm volatile("s_waitcnt vmcnt(4)" ::: "memory"); // B(kb) landed
        } else {
            asm volatile("s_waitcnt vmcnt(0)" ::: "memory"); // tail: drain all
        }
        __builtin_amdgcn_sched_barrier(0);
        COMPUTE(breg, a);
        if (kb + 1 < 12) ISSUE_B(breg, kb + 1);
    }
#undef STAGE64
#undef ISSUE_B
#undef READ_A
#undef COMPUTE

    // epilogue: bias, norms (reduce across 16 lanes sharing a C-row), pack
    float bpv[8];
#pragma unroll
    for (int cb = 0; cb < 8; ++cb) bpv[cb] = bp[cb * 16 + li];
#pragma unroll
    for (int cb = 0; cb < 8; ++cb)
#pragma unroll
        for (int r = 0; r < 4; ++r) acc[cb][r] += bpv[cb];

#pragma unroll
    for (int r = 0; r < 4; ++r) {
        float s = 0.f;
#pragma unroll
        for (int cb = 0; cb < 8; ++cb) {
            float v = acc[cb][r];
            s += v * v;
        }
        s += __shfl_xor(s, 1);
        s += __shfl_xor(s, 2);
        s += __shfl_xor(s, 4);
        s += __shfl_xor(s, 8);
        int grow = rowblk + w * 16 + 4 * g + r;
        if (li == 0) normv[grow] = (grow < Mreal) ? s : 1e30f;
    }

#pragma unroll
    for (int cb = 0; cb < 8; ++cb) {
        int d = cb * 16 + li;
        int q = d >> 5, g2 = (d & 31) >> 3, j = d & 7;
#pragma unroll
        for (int r = 0; r < 4; ++r) {
            int grow = rowblk + w * 16 + 4 * g + r;
            float v = (grow < Mreal) ? acc[cb][r] : 0.f;
            size_t e = ((size_t)((grow >> 4) * 4 + q) * 64 +
                        (g2 * 16 + (grow & 15))) * 8 + j;
            outP[e] = f2bf(v);
        }
    }
}

// ---------------------------------------------------------------------------
// Kernel 4: main fused kernel. Grid (NCH, 8): ch = blockIdx.x (XCD = ch%8),
// bt = blockIdx.y. Per i-tile: S = px @ pX^T via MFMA (B-frags double-buffered
// across unrolled ib; kn/lab prefetched per tile), Kis = exp(-(qn+kn-2dot)/256),
// drop-self, fixed-point ds_add_u32 bins by lab[i]; plain stores to partials.
// ---------------------------------------------------------------------------
__global__ __launch_bounds__(256) void k_main(const short* __restrict__ pxp,
                                              const short* __restrict__ pXp,
                                              const float* __restrict__ qn,
                                              const float* __restrict__ kn,
                                              const int* __restrict__ lab,
                                              float* __restrict__ part,
                                              int NCH) {
    __shared__ __align__(16) unsigned plds[128 * PSTRIDE];   // u32 fixed-point bins
    const int tid = threadIdx.x;
    const int w = tid >> 6, l = tid & 63, g = l >> 4, li = l & 15;
    const int ch = blockIdx.x;
    const int bt = blockIdx.y;       // 0..7

    for (int s = tid; s < 128 * PSTRIDE; s += 256) plds[s] = 0u;
    __syncthreads();                 // only barrier in the kernel

    bf8v af[2][4];                   // px A-frags, persistent
#pragma unroll
    for (int rb = 0; rb < 2; ++rb)
#pragma unroll
        for (int q = 0; q < 4; ++q) {
            int RB = bt * 8 + w * 2 + rb;
            af[rb][q] = *reinterpret_cast<const bf8v*>(
                            pxp + (size_t)((RB * 4 + q) * 64 + l) * 8);
        }
    float qnv[2][4];
#pragma unroll
    for (int rb = 0; rb < 2; ++rb)
#pragma unroll
        for (int r = 0; r < 4; ++r)
            qnv[rb][r] = qn[bt * 128 + w * 32 + rb * 16 + 4 * g + r];

#pragma unroll 1
    for (int t = ch; t < NTILES; t += NCH) {
        const int i0 = t * 128;
        float knv8[8];
        int   labv8[8];
#pragma unroll
        for (int ib = 0; ib < 8; ++ib) {
            knv8[ib]  = kn[i0 + ib * 16 + li];
            labv8[ib] = lab[i0 + ib * 16 + li];
        }
        bf8v bfr2[2][4];
        {
            const int RBi = (i0 >> 4);
#pragma unroll
            for (int q = 0; q < 4; ++q)
                bfr2[0][q] = *reinterpret_cast<const bf8v*>(
                                 pXp + (size_t)((RBi * 4 + q) * 64 + l) * 8);
        }
#pragma unroll
        for (int ib = 0; ib < 8; ++ib) {
            if (ib < 7) {                         // prefetch next sub-tile
                const int RBn = (i0 >> 4) + ib + 1;
#pragma unroll
                for (int q = 0; q < 4; ++q)
                    bfr2[(ib + 1) & 1][q] = *reinterpret_cast<const bf8v*>(
                        pXp + (size_t)((RBn * 4 + q) * 64 + l) * 8);
            }
            f32x4 s0 = (f32x4){0.f, 0.f, 0.f, 0.f};
            f32x4 s1 = (f32x4){0.f, 0.f, 0.f, 0.f};
#pragma unroll
            for (int q = 0; q < 4; ++q) {
                s0 = __builtin_amdgcn_mfma_f32_16x16x32_bf16(af[0][q], bfr2[ib & 1][q], s0, 0, 0, 0);
                s1 = __builtin_amdgcn_mfma_f32_16x16x32_bf16(af[1][q], bfr2[ib & 1][q], s1, 0, 0, 0);
            }
            const float knv  = knv8[ib];
            const int   labv = labv8[ib];
#pragma unroll
            for (int rb = 0; rb < 2; ++rb) {
                f32x4 sv = rb ? s1 : s0;
#pragma unroll
                for (int r = 0; r < 4; ++r) {
                    float sqd = qnv[rb][r] + knv - 2.f * sv[r];
                    float kis = __expf(sqd * (-1.f / 256.f));
                    kis = (kis < 1.0f) ? kis : 0.f;   // drop_self (1-1e-10 == 1.0f)
                    unsigned qv = (unsigned)__float2uint_rn(kis * FIXS);
                    int rowl = w * 32 + rb * 16 + 4 * g + r;
                    atomicAdd(&plds[rowl * PSTRIDE + labv], qv);   // ds_add_u32
                }
            }
        }
    }

    // epilogue: each wave flushes its own rows with plain vectorized stores
#pragma unroll 1
    for (int rr = 0; rr < 32; ++rr) {
        int row = w * 32 + rr;
        if (l < PCOLS / 2) {
            uint2 u = *reinterpret_cast<const uint2*>(&plds[row * PSTRIDE + l * 2]);
            float2 v = make_float2((float)u.x * FIXI, (float)u.y * FIXI);
            int grow = bt * 128 + row;
            *reinterpret_cast<float2*>(
                &part[((size_t)grow * NCH + ch) * PCOLS + l * 2]) = v;
        }
    }
}

// ---------------------------------------------------------------------------
// Kernel 5: fused reduce + normalize + rank-gather. 256 threads: halves
// h=0/1 each sum NCH/2 chunks (deterministic), combine, then rank-gather.
// ---------------------------------------------------------------------------
__global__ __launch_bounds__(256) void k_final(const float* __restrict__ part,
                                               const float* __restrict__ SorPq,
                                               float* __restrict__ out,
                                               int NCH) {
    __shared__ float sp[NCLS];
    __shared__ float pr2[2][PCOLS];
    int t = threadIdx.x, b = blockIdx.x;
    int c = t & 127, h = t >> 7;
    if (h == 1 && c < NCLS) sp[c] = SorPq[(size_t)b * NCLS + c];
    if (c < PCOLS) {
        float s = 0.f;
        int half = NCH >> 1;
        const float* p = part + ((size_t)b * NCH + (size_t)h * half) * PCOLS + c;
        for (int ch = 0; ch < half; ++ch) s += p[(size_t)ch * PCOLS];
        pr2[h][c] = s;
    }
    __syncthreads();
    if (t < PCOLS) pr2[0][t] += pr2[1][t];
    __syncthreads();
    if (t < NCLS) {
        float tot = 0.f;
        for (int k = 0; k < NCLS; ++k) tot += pr2[0][k];  // broadcast, deterministic
        float s = sp[t];
        int r = 0;
        for (int k = 0; k < NCLS; ++k) {
            float sk = sp[k];
            r += (sk > s || (sk == s && k < t)) ? 1 : 0;
        }
        out[(size_t)b * NCLS + t] = pr2[0][r] / tot;
    }
}

// ---------------------------------------------------------------------------
extern "C" void kernel_launch(void* const* d_in, const int* in_sizes, int n_in,
                              void* d_out, int out_size, void* d_ws, size_t ws_size,
                              hipStream_t stream) {
    const float* x    = (const float*)d_in[0];   // [1024,768]
    const float* X    = (const float*)d_in[1];   // [50000,768]
    const float* Wp   = (const float*)d_in[2];   // [768,128]
    const float* bp   = (const float*)d_in[3];   // [128]
    const int*   Y    = (const int*)  d_in[4];   // [50000]
    const float* SPt  = (const float*)d_in[5];   // [50000,100]
    const float* SPq  = (const float*)d_in[6];   // [1024,100]
    float* out = (float*)d_out;                  // [1024,100]

    char* ws = (char*)d_ws;
    short* WpP = (short*)(ws + 0);                       //   196,608
    short* pXp = (short*)(ws + 196608);                  // 12,812,288
    short* pxq = (short*)(ws + 13008896);                //    262,144
    float* kn  = (float*)(ws + 13271040);                //    200,192
    float* qn  = (float*)(ws + 13471232);                //      4,096
    int*   lab = (int*)  (ws + 13475328);                //    200,192
    float* part= (float*)(ws + 13675520);                // NCH*1024*104*4

    const size_t base = 13675520;
    const size_t per  = (size_t)BQ * PCOLS * 4;
    int NCH = 96;
    if (ws_size > base) {
        size_t fit = (ws_size - base) / per;
        if ((size_t)NCH > fit) NCH = (int)fit;
    } else {
        NCH = 8;
    }
    NCH &= ~7;
    if (NCH < 8) NCH = 8;

    k_prep<<<48 + (NPAD + 3) / 4, 256, 0, stream>>>(Wp, WpP, SPt, Y, lab);
    k_proj<<<NPAD / 64, 256, 0, stream>>>(X, WpP, bp, pXp, kn, NTRAIN);
    k_proj<<<(BQ + 63) / 64, 256, 0, stream>>>(x, WpP, bp, pxq, qn, BQ);
    k_main<<<dim3(NCH, 8), 256, 0, stream>>>(pxq, pXp, qn, kn, lab, part, NCH);
    k_final<<<BQ, 256, 0, stream>>>(part, SPq, out, NCH);
}

// Round 13
// 111.884 us; speedup vs baseline: 1.6155x; 1.1112x over previous
//
#include <hip/hip_runtime.h>

// ---------------------------------------------------------------------------
// KernelClassifier: px = x@Wp+bp; pX = X@Wp+bp; Kis = exp(-||px-pX||^2/256)
// (drop self: Kis<1.0f), pred[b,lab[i]] += Kis[b,i], normalize, rank-gather.
// R4: LDS fp32 atomicAdd = CAS loop -> fixed-point ds_add_u32 (451->216us).
// R11/R12: per-wave counted-vmcnt pipeline in k_proj + occupancy/final/prep
//     (216->124us). Profile-pass k_proj ~86us is a cold-L3 artifact (poison
//     fills evict X between profiled replays; timed replays keep X L3-hot).
// R13: (a) k_main pXp B-frag ring depth 4 (L3 ~500cyc vs 1-ib ~100cyc);
//     (b) PSTRIDE 104->102: 104≡8 mod 32 made the 4 g-lanes same-bank on
//     every ds_add (4x conflict); 102≡6 spreads, still 3 blocks/CU;
//     (c) merge projX+projx+labels into k_front (projX blocks first).
// ---------------------------------------------------------------------------

typedef short  bf8v  __attribute__((ext_vector_type(8)));   // 8 x bf16 (4 VGPR)
typedef float  f32x4 __attribute__((ext_vector_type(4)));   // MFMA C/D

#define NTRAIN 50000
#define NPAD   50048          // 391 * 128
#define NTILES 391
#define BQ     1024
#define DIN    768
#define DP     128
#define NCLS   100
#define PSTRIDE 102           // LDS bins stride: 102%32=6, 4*6%32!=0 -> the 4
                              // g-lanes of one (rb,r) hit distinct banks.
                              // 128*102*4 = 52224B -> still 3 blocks/CU.
#define PCOLS  104            // partial row width (float2-aligned)
#define FIXS   2097152.0f     // 2^21 fixed-point scale
#define FIXI   (1.0f / 2097152.0f)
#define NBX    (NPAD / 64)    // 782 projX blocks
#define NBQ    (BQ / 64)      // 16 projx blocks
#define NBL    ((NPAD + 3) / 4)

__device__ __forceinline__ short f2bf(float x) {   // fp32 -> bf16 RNE
    unsigned u = __float_as_uint(x);
    u += 0x7FFFu + ((u >> 16) & 1u);
    return (short)(u >> 16);
}

#define AS1U(p) ((const __attribute__((address_space(1))) unsigned int*)(unsigned long long)(p))
#define AS3U(p) ((__attribute__((address_space(3))) unsigned int*)(unsigned int)(unsigned long long)(p))

// ---------------------------------------------------------------------------
// Kernel 0: pack Wp into B-fragment order (WpP must precede k_front's proj)
// ---------------------------------------------------------------------------
__global__ __launch_bounds__(256) void k_pack_wp(const float* __restrict__ Wp,
                                                 short* __restrict__ WpP) {
    int tid = blockIdx.x * 256 + threadIdx.x;
    if (tid >= 24 * 8 * 64) return;
    int l = tid & 63, cb = (tid >> 6) & 7, q = tid >> 9;
    int c = cb * 16 + (l & 15);
    int g = l >> 4;
    bf8v o;
#pragma unroll
    for (int j = 0; j < 8; ++j) {
        int k = q * 32 + g * 8 + j;
        o[j] = f2bf(Wp[k * DP + c]);
    }
    *reinterpret_cast<bf8v*>(WpP + (size_t)tid * 8) = o;
}

// ---------------------------------------------------------------------------
// proj body (R12 pipeline): BM=64, 4 waves, barrier-free, counted vmcnt.
// ---------------------------------------------------------------------------
__device__ __forceinline__ void proj_body(const float* __restrict__ Xin,
                                          const short* __restrict__ WpP,
                                          const float* __restrict__ bp,
                                          short* __restrict__ outP,
                                          float* __restrict__ normv,
                                          int Mreal, int blk,
                                          float* __restrict__ Xlds) {
    const int tid = threadIdx.x;
    const int w = tid >> 6, l = tid & 63, g = l >> 4, li = l & 15;
    const int rowblk = blk * 64;

    f32x4 acc[8];
#pragma unroll
    for (int cb = 0; cb < 8; ++cb) acc[cb] = (f32x4){0.f, 0.f, 0.f, 0.f};

#define STAGE64(lbuf, kb)                                                     \
    {                                                                         \
        _Pragma("unroll")                                                     \
        for (int it = 0; it < 4; ++it) {                                      \
            int s  = w * 256 + it * 64 + l;                                   \
            int r  = s >> 4;                                                  \
            int c4 = (s & 15) ^ (r & 7);                                      \
            int rg = rowblk + r;                                              \
            rg = (rg < Mreal) ? rg : (Mreal - 1);                             \
            const float* gp = Xin + (size_t)rg * DIN + (kb) * 64 + c4 * 4;    \
            const float* lp = (lbuf) + (w * 256 + it * 64) * 4;               \
            __builtin_amdgcn_global_load_lds(AS1U(gp), AS3U(lp), 16, 0, 0);   \
        }                                                                     \
    }
#define ISSUE_B(dst, kb)                                                      \
    {                                                                         \
        _Pragma("unroll")                                                     \
        for (int f = 0; f < 16; ++f)                                          \
            dst[f] = *reinterpret_cast<const bf8v*>(                          \
                WpP + ((size_t)((kb) * 16 + f) * 64 + l) * 8);                \
    }

    bf8v breg[16];
    float4 a[4];

    STAGE64(Xlds, 0);
    STAGE64(Xlds + 4096, 1);
    ISSUE_B(breg, 0);

#pragma unroll 1
    for (int kb = 0; kb < 12; ++kb) {
        float* tb = Xlds + (kb & 1) * 4096;
        asm volatile("s_waitcnt vmcnt(20)" ::: "memory");   // A(kb) landed
        {
            const float* rbase = tb + (w * 16 + li) * 64;
#pragma unroll
            for (int kc = 0; kc < 2; ++kc) {
                int s0 = (kc * 8 + g * 2)     ^ (li & 7);
                int s1 = (kc * 8 + g * 2 + 1) ^ (li & 7);
                a[kc * 2]     = *reinterpret_cast<const float4*>(rbase + s0 * 4);
                a[kc * 2 + 1] = *reinterpret_cast<const float4*>(rbase + s1 * 4);
            }
        }
        asm volatile("s_waitcnt lgkmcnt(0)" ::: "memory");  // reads retired
        __builtin_amdgcn_sched_barrier(0);
        if (kb + 2 < 12) {
            STAGE64(tb, kb + 2);
            asm volatile("s_waitcnt vmcnt(4)" ::: "memory"); // B(kb) landed
        } else {
            asm volatile("s_waitcnt vmcnt(0)" ::: "memory"); // tail drain
        }
        __builtin_amdgcn_sched_barrier(0);
#pragma unroll
        for (int kc = 0; kc < 2; ++kc) {
            float4 a0 = a[kc * 2], a1 = a[kc * 2 + 1];
            bf8v af;
            af[0] = f2bf(a0.x); af[1] = f2bf(a0.y);
            af[2] = f2bf(a0.z); af[3] = f2bf(a0.w);
            af[4] = f2bf(a1.x); af[5] = f2bf(a1.y);
            af[6] = f2bf(a1.z); af[7] = f2bf(a1.w);
#pragma unroll
            for (int cb = 0; cb < 8; ++cb)
                acc[cb] = __builtin_amdgcn_mfma_f32_16x16x32_bf16(
                              af, breg[kc * 8 + cb], acc[cb], 0, 0, 0);
        }
        if (kb + 1 < 12) ISSUE_B(breg, kb + 1);
    }
#undef STAGE64
#undef ISSUE_B

    // epilogue: bias, norms, pack
    float bpv[8];
#pragma unroll
    for (int cb = 0; cb < 8; ++cb) bpv[cb] = bp[cb * 16 + li];
#pragma unroll
    for (int cb = 0; cb < 8; ++cb)
#pragma unroll
        for (int r = 0; r < 4; ++r) acc[cb][r] += bpv[cb];

#pragma unroll
    for (int r = 0; r < 4; ++r) {
        float s = 0.f;
#pragma unroll
        for (int cb = 0; cb < 8; ++cb) {
            float v = acc[cb][r];
            s += v * v;
        }
        s += __shfl_xor(s, 1);
        s += __shfl_xor(s, 2);
        s += __shfl_xor(s, 4);
        s += __shfl_xor(s, 8);
        int grow = rowblk + w * 16 + 4 * g + r;
        if (li == 0) normv[grow] = (grow < Mreal) ? s : 1e30f;
    }

#pragma unroll
    for (int cb = 0; cb < 8; ++cb) {
        int d = cb * 16 + li;
        int q = d >> 5, g2 = (d & 31) >> 3, j = d & 7;
#pragma unroll
        for (int r = 0; r < 4; ++r) {
            int grow = rowblk + w * 16 + 4 * g + r;
            float v = (grow < Mreal) ? acc[cb][r] : 0.f;
            size_t e = ((size_t)((grow >> 4) * 4 + q) * 64 +
                        (g2 * 16 + (grow & 15))) * 8 + j;
            outP[e] = f2bf(v);
        }
    }
}

// ---------------------------------------------------------------------------
// Kernel 1: k_front — blocks [0,NBX): projX; [NBX,NBX+NBQ): projx;
// rest: labels (stable descending rank of SorP_train[i, Y[i]]).
// projX first so the long pole starts dispatching immediately.
// ---------------------------------------------------------------------------
__global__ __launch_bounds__(256, 3) void k_front(const float* __restrict__ X,
                                                  const float* __restrict__ x,
                                                  const short* __restrict__ WpP,
                                                  const float* __restrict__ bp,
                                                  short* __restrict__ pXp,
                                                  short* __restrict__ pxq,
                                                  float* __restrict__ kn,
                                                  float* __restrict__ qn,
                                                  const float* __restrict__ S,
                                                  const int* __restrict__ Y,
                                                  int* __restrict__ lab) {
    __shared__ __align__(16) float Xlds[2 * 64 * 64];   // 32 KB
    int b = blockIdx.x;
    if (b < NBX) {
        proj_body(X, WpP, bp, pXp, kn, NTRAIN, b, Xlds);
        return;
    }
    if (b < NBX + NBQ) {
        proj_body(x, WpP, bp, pxq, qn, BQ, b - NBX, Xlds);
        return;
    }
    int w = threadIdx.x >> 6, l = threadIdx.x & 63;
    int i = (b - NBX - NBQ) * 4 + w;
    if (i >= NPAD) return;
    int cnt = 0;
    if (i < NTRAIN) {
        int y = Y[i];
        float t = S[(size_t)i * NCLS + y];
        float v1 = S[(size_t)i * NCLS + l];
        bool p1 = (v1 > t) || (v1 == t && l < y);
        unsigned long long b1 = __ballot(p1);
        bool p2 = false;
        if (l < NCLS - 64) {
            float v2 = S[(size_t)i * NCLS + 64 + l];
            p2 = (v2 > t) || (v2 == t && (64 + l) < y);
        }
        unsigned long long b2 = __ballot(p2);
        cnt = __popcll(b1) + __popcll(b2);
    }
    if (l == 0) lab[i] = cnt;
}

// ---------------------------------------------------------------------------
// Kernel 4: main fused kernel. Grid (NCH, 8). Per i-tile: kn/lab prefetch,
// pXp B-frag ring depth 4 (prefetch 3 ib ahead, static idx via full unroll),
// 8 MFMA, Kis = exp(-(qn+kn-2dot)/256), drop-self, ds_add_u32 bins (stride
// 102), plain stores to per-chunk partials.
// ---------------------------------------------------------------------------
__global__ __launch_bounds__(256) void k_main(const short* __restrict__ pxp,
                                              const short* __restrict__ pXp,
                                              const float* __restrict__ qn,
                                              const float* __restrict__ kn,
                                              const int* __restrict__ lab,
                                              float* __restrict__ part,
                                              int NCH) {
    __shared__ __align__(16) unsigned plds[128 * PSTRIDE];   // 52224 B
    const int tid = threadIdx.x;
    const int w = tid >> 6, l = tid & 63, g = l >> 4, li = l & 15;
    const int ch = blockIdx.x;
    const int bt = blockIdx.y;       // 0..7

    for (int s = tid; s < 128 * PSTRIDE; s += 256) plds[s] = 0u;
    __syncthreads();                 // only barrier in the kernel

    bf8v af[2][4];                   // px A-frags, persistent
#pragma unroll
    for (int rb = 0; rb < 2; ++rb)
#pragma unroll
        for (int q = 0; q < 4; ++q) {
            int RB = bt * 8 + w * 2 + rb;
            af[rb][q] = *reinterpret_cast<const bf8v*>(
                            pxp + (size_t)((RB * 4 + q) * 64 + l) * 8);
        }
    float qnv[2][4];
#pragma unroll
    for (int rb = 0; rb < 2; ++rb)
#pragma unroll
        for (int r = 0; r < 4; ++r)
            qnv[rb][r] = qn[bt * 128 + w * 32 + rb * 16 + 4 * g + r];

#pragma unroll 1
    for (int t = ch; t < NTILES; t += NCH) {
        const int i0 = t * 128;
        const int RB0 = i0 >> 4;
        float knv8[8];
        int   labv8[8];
#pragma unroll
        for (int ib = 0; ib < 8; ++ib) {
            knv8[ib]  = kn[i0 + ib * 16 + li];
            labv8[ib] = lab[i0 + ib * 16 + li];
        }
        // B-frag ring: 3 sub-tiles in flight
        bf8v bfr[4][4];
#pragma unroll
        for (int p = 0; p < 3; ++p)
#pragma unroll
            for (int q = 0; q < 4; ++q)
                bfr[p][q] = *reinterpret_cast<const bf8v*>(
                    pXp + (size_t)(((RB0 + p) * 4 + q) * 64 + l) * 8);
#pragma unroll
        for (int ib = 0; ib < 8; ++ib) {
            if (ib + 3 < 8) {
#pragma unroll
                for (int q = 0; q < 4; ++q)
                    bfr[(ib + 3) & 3][q] = *reinterpret_cast<const bf8v*>(
                        pXp + (size_t)(((RB0 + ib + 3) * 4 + q) * 64 + l) * 8);
            }
            f32x4 s0 = (f32x4){0.f, 0.f, 0.f, 0.f};
            f32x4 s1 = (f32x4){0.f, 0.f, 0.f, 0.f};
#pragma unroll
            for (int q = 0; q < 4; ++q) {
                s0 = __builtin_amdgcn_mfma_f32_16x16x32_bf16(af[0][q], bfr[ib & 3][q], s0, 0, 0, 0);
                s1 = __builtin_amdgcn_mfma_f32_16x16x32_bf16(af[1][q], bfr[ib & 3][q], s1, 0, 0, 0);
            }
            const float knv  = knv8[ib];
            const int   labv = labv8[ib];
#pragma unroll
            for (int rb = 0; rb < 2; ++rb) {
                f32x4 sv = rb ? s1 : s0;
#pragma unroll
                for (int r = 0; r < 4; ++r) {
                    float sqd = qnv[rb][r] + knv - 2.f * sv[r];
                    float kis = __expf(sqd * (-1.f / 256.f));
                    kis = (kis < 1.0f) ? kis : 0.f;   // drop_self (1-1e-10 == 1.0f)
                    unsigned qv = (unsigned)__float2uint_rn(kis * FIXS);
                    int rowl = w * 32 + rb * 16 + 4 * g + r;
                    atomicAdd(&plds[rowl * PSTRIDE + labv], qv);   // ds_add_u32
                }
            }
        }
    }

    // epilogue: flush 102 cols/row (labv < 100 so cols 100-101 are zero)
#pragma unroll 1
    for (int rr = 0; rr < 32; ++rr) {
        int row = w * 32 + rr;
        if (l < PSTRIDE / 2) {
            uint2 u = *reinterpret_cast<const uint2*>(&plds[row * PSTRIDE + l * 2]);
            float2 v = make_float2((float)u.x * FIXI, (float)u.y * FIXI);
            int grow = bt * 128 + row;
            *reinterpret_cast<float2*>(
                &part[((size_t)grow * NCH + ch) * PCOLS + l * 2]) = v;
        }
    }
}

// ---------------------------------------------------------------------------
// Kernel 5: fused reduce + normalize + rank-gather. 256 threads, 2-way split
// reduction (only c<NCLS needed; part cols >=102 are never written).
// ---------------------------------------------------------------------------
__global__ __launch_bounds__(256) void k_final(const float* __restrict__ part,
                                               const float* __restrict__ SorPq,
                                               float* __restrict__ out,
                                               int NCH) {
    __shared__ float sp[NCLS];
    __shared__ float pr2[2][PCOLS];
    int t = threadIdx.x, b = blockIdx.x;
    int c = t & 127, h = t >> 7;
    if (h == 1 && c < NCLS) sp[c] = SorPq[(size_t)b * NCLS + c];
    if (c < NCLS) {
        float s = 0.f;
        int half = NCH >> 1;
        const float* p = part + ((size_t)b * NCH + (size_t)h * half) * PCOLS + c;
        for (int ch = 0; ch < half; ++ch) s += p[(size_t)ch * PCOLS];
        pr2[h][c] = s;
    }
    __syncthreads();
    if (t < NCLS) pr2[0][t] += pr2[1][t];
    __syncthreads();
    if (t < NCLS) {
        float tot = 0.f;
        for (int k = 0; k < NCLS; ++k) tot += pr2[0][k];  // broadcast, deterministic
        float s = sp[t];
        int r = 0;
        for (int k = 0; k < NCLS; ++k) {
            float sk = sp[k];
            r += (sk > s || (sk == s && k < t)) ? 1 : 0;
        }
        out[(size_t)b * NCLS + t] = pr2[0][r] / tot;
    }
}

// ---------------------------------------------------------------------------
extern "C" void kernel_launch(void* const* d_in, const int* in_sizes, int n_in,
                              void* d_out, int out_size, void* d_ws, size_t ws_size,
                              hipStream_t stream) {
    const float* x    = (const float*)d_in[0];   // [1024,768]
    const float* X    = (const float*)d_in[1];   // [50000,768]
    const float* Wp   = (const float*)d_in[2];   // [768,128]
    const float* bp   = (const float*)d_in[3];   // [128]
    const int*   Y    = (const int*)  d_in[4];   // [50000]
    const float* SPt  = (const float*)d_in[5];   // [50000,100]
    const float* SPq  = (const float*)d_in[6];   // [1024,100]
    float* out = (float*)d_out;                  // [1024,100]

    char* ws = (char*)d_ws;
    short* WpP = (short*)(ws + 0);                       //   196,608
    short* pXp = (short*)(ws + 196608);                  // 12,812,288
    short* pxq = (short*)(ws + 13008896);                //    262,144
    float* kn  = (float*)(ws + 13271040);                //    200,192
    float* qn  = (float*)(ws + 13471232);                //      4,096
    int*   lab = (int*)  (ws + 13475328);                //    200,192
    float* part= (float*)(ws + 13675520);                // NCH*1024*104*4

    const size_t base = 13675520;
    const size_t per  = (size_t)BQ * PCOLS * 4;
    int NCH = 96;
    if (ws_size > base) {
        size_t fit = (ws_size - base) / per;
        if ((size_t)NCH > fit) NCH = (int)fit;
    } else {
        NCH = 8;
    }
    NCH &= ~7;
    if (NCH < 8) NCH = 8;

    k_pack_wp<<<48, 256, 0, stream>>>(Wp, WpP);
    k_front<<<NBX + NBQ + NBL, 256, 0, stream>>>(X, x, WpP, bp, pXp, pxq,
                                                 kn, qn, SPt, Y, lab);
    k_main<<<dim3(NCH, 8), 256, 0, stream>>>(pxq, pXp, qn, kn, lab, part, NCH);
    k_final<<<BQ, 256, 0, stream>>>(part, SPq, out, NCH);
}